// Round 14
// baseline (274.294 us; speedup 1.0000x reference)
//
#include <hip/hip_runtime.h>

// SpanRepresentation R13: INSTRUMENTATION build (will revert).
// R8 LDS-decoupled kernel + ~100us dependent-FMA delay between staging and
// the store stream. Memory behavior identical to R8; the delay only makes our
// dispatch longer than the harness's 121us poison fills so its FETCH_SIZE /
// WRITE_SIZE / VALUBusy / Occupancy finally appear in the top-5.
// Decider: FETCH_SIZE ~200MB => write-allocate/RFO on store misses (fix: NT
// stores). FETCH_SIZE ~13MB => no RFO; store-miss path is the cap.

typedef float f4 __attribute__((ext_vector_type(4)));

#define L_DIM 512
#define S_TOT 4068
#define ROW4  389
#define D4    192

#define CW_LO ((1533ull << 48) | (1023ull << 32) | (512ull << 16) | 0ull)
#define CW_HI ((3563ull << 48) | (3057ull << 32) | (2550ull << 16) | 2042ull)
__device__ __forceinline__ int cw_of(int k) {  // k = w-1, 0..7
    return (int)(((k < 4 ? CW_LO : CW_HI) >> (16 * (k & 3))) & 0xFFFF);
}

__global__ __launch_bounds__(256) void span_rep_probe(
    const f4* __restrict__ x,
    const f4* __restrict__ we,
    f4* __restrict__ out)
{
    __shared__ f4 lx[D4];
    __shared__ f4 lw[40];

    const int r = blockIdx.x;
    const int b = blockIdx.y;
    const int t = (int)threadIdx.x;

    // ---- stage (only global loads) ----
    if (t < D4) {
        lx[t] = x[((size_t)b * L_DIM + r) * D4 + t];
    } else if (t < D4 + 40) {
        const int u = t - D4;
        const int w = u / 5 + 1;
        const int col = u - (w - 1) * 5;
        const int bucket = (int)((0x765543210ull >> (4 * w)) & 0xF);
        lw[u] = we[bucket * 5 + col];
    }
    __syncthreads();

    // ---- pure-VALU delay: dependent FMA chain, no memory side effects ----
    {
        float acc = lx[t & (D4 - 1)].x;   // data-dependent seed
        for (int i = 0; i < 6000; ++i)
            acc = __builtin_fmaf(acc, 1.0000001f, 1e-7f);
        asm volatile("" :: "v"(acc));     // keep chain live (rule #17)
    }

    // ---- store stream, identical to R8 ----
    const size_t outB = (size_t)b * S_TOT;

    #pragma unroll
    for (int i = 0; i < 12; ++i) {
        const int u = i * 256 + t;
        const int q = (u >> 6) / 3;
        const int e = u - q * 192;
        const int w = (q & 7) + 1;
        const int cw = cw_of(q & 7);
        if (q < 8) {
            if (r + w <= L_DIM)
                out[(outB + cw + r) * ROW4 + e] = lx[e];
        } else {
            if (r >= w - 1)
                out[(outB + cw + r - w + 1) * ROW4 + D4 + e] = lx[e];
        }
    }
    if (t < 40) {
        const int w = t / 5 + 1;
        const int col = t - (w - 1) * 5;
        if (r + w <= L_DIM)
            out[(outB + cw_of(w - 1) + r) * ROW4 + 2 * D4 + col] = lw[t];
    }
}

extern "C" void kernel_launch(void* const* d_in, const int* in_sizes, int n_in,
                              void* d_out, int out_size, void* d_ws, size_t ws_size,
                              hipStream_t stream) {
    const f4* x  = (const f4*)d_in[0];
    const f4* we = (const f4*)d_in[1];
    f4* out = (f4*)d_out;

    dim3 grid(L_DIM, 8);
    span_rep_probe<<<grid, 256, 0, stream>>>(x, we, out);
}